// Round 3
// baseline (318.945 us; speedup 1.0000x reference)
//
#include <hip/hip_runtime.h>
#include <hip/hip_bf16.h>

// Problem constants (B,R,N,D,O) = (64,32,16384,64,8)
// Dtype model (R1/R2 evidence): float tensors are fp32 buffers (R1 u16 reads -> NaN),
// o_types/center_o are int32 (explicit dtype in reference), masks are bool ->
// EITHER int32 0/1 or 1-byte bools (auto-detected below), output = fp32
// (reference returns float32; harness doc: output dtype follows reference).
constexpr int kB = 64;
constexpr int kR = 32;
constexpr int kN = 16384;
constexpr int kD = 64;
constexpr int kO = 8;
constexpr int kChunks = 16;                    // blocks per batch in kernel 1
constexpr int kRowsPerBlock = kN / kChunks;    // 1024
constexpr int kAccStride = kD + 1;             // 64 vec elems + 1 count per batch
constexpr int kMaskWords = kB * kN / 4;        // 262144 u32 words = full byte-bool array
constexpr size_t kFlagOff = (size_t)kB * kAccStride * sizeof(float);  // 16640

// Pre-pass: decide whether masks are 1-byte bools or int32 0/1.
// Reads only the first B*N BYTES of each buffer (valid under both layouts).
// int32 0/1 arrays contain only word values {0,1}; byte-bool arrays contain
// words >1 with ~14% probability per word -> detection is statistically certain.
__global__ __launch_bounds__(256) void ssfw_detect(
    const unsigned* __restrict__ adj, const unsigned* __restrict__ two,
    int* __restrict__ flag)
{
    int any = 0;
    for (int i = blockIdx.x * blockDim.x + threadIdx.x; i < kMaskWords;
         i += gridDim.x * blockDim.x) {
        any |= (adj[i] > 1u) | (two[i] > 1u);
    }
    if (__any(any)) {
        if ((threadIdx.x & 63) == 0) atomicOr(flag, 1);
    }
}

// Kernel 1: per (b, chunk): scan masks, collect valid rows in LDS, then
// accumulate v[d] += h[row,d]/||h[row]|| only over valid rows (~0.74% of N).
__global__ __launch_bounds__(256) void ssfw_accum(
    const float* __restrict__ h,               // [B,N,D] f32
    const int* __restrict__ o_types,           // [B,N] int32
    const int* __restrict__ center_o,          // [B] int32
    const void* __restrict__ adj,              // [B,N] int32 or byte bool
    const void* __restrict__ two,              // [B,N] int32 or byte bool
    const int* __restrict__ flag,              // 0 = int32 masks, 1 = byte masks
    float* __restrict__ gacc)                  // [B, kAccStride] f32
{
    const int b     = blockIdx.y;
    const int chunk = blockIdx.x;
    const int tid   = threadIdx.x;
    const int wave  = tid >> 6;
    const int lane  = tid & 63;
    const int sub   = lane >> 4;   // which of 4 rows this lane helps with
    const int dq    = lane & 15;   // which float4 of the 64-float row

    const int  ctr      = center_o[b];
    const bool bytemask = (*flag != 0);
    const int  row0     = chunk * kRowsPerBlock;
    const float* hb     = h + (size_t)b * kN * kD;

    __shared__ int   slist[kRowsPerBlock];
    __shared__ int   lcnt;
    __shared__ float sacc[4][kD];

    if (tid == 0) lcnt = 0;
    __syncthreads();

    // Phase A: mask scan — thread t checks rows r..r+3.
    {
        const int r = row0 + tid * 4;
        const size_t base = (size_t)b * kN + r;
        int a[4], t[4];
        if (bytemask) {
            const unsigned aw = reinterpret_cast<const unsigned*>(adj)[base >> 2];
            const unsigned tw = reinterpret_cast<const unsigned*>(two)[base >> 2];
            a[0] = aw & 0xff; a[1] = (aw >> 8) & 0xff;
            a[2] = (aw >> 16) & 0xff; a[3] = aw >> 24;
            t[0] = tw & 0xff; t[1] = (tw >> 8) & 0xff;
            t[2] = (tw >> 16) & 0xff; t[3] = tw >> 24;
        } else {
            const int4 a4 = reinterpret_cast<const int4*>(adj)[base >> 2];
            const int4 t4 = reinterpret_cast<const int4*>(two)[base >> 2];
            a[0] = a4.x; a[1] = a4.y; a[2] = a4.z; a[3] = a4.w;
            t[0] = t4.x; t[1] = t4.y; t[2] = t4.z; t[3] = t4.w;
        }
        const int4 o4 = reinterpret_cast<const int4*>(o_types)[base >> 2];
        const int oo[4] = {o4.x, o4.y, o4.z, o4.w};
#pragma unroll
        for (int k = 0; k < 4; ++k) {
            if (((a[k] | t[k]) != 0) && (oo[k] == ctr)) {
                const int p = atomicAdd(&lcnt, 1);
                slist[p] = r + k;
            }
        }
    }
    __syncthreads();
    const int cnt = lcnt;

    // Phase B: process valid rows; 4 rows per wave-iter, 16 lanes per row.
    float acc[4] = {0.f, 0.f, 0.f, 0.f};
    for (int base = wave * 4; base < cnt; base += 16) {
        const int  idx = base + sub;
        const bool act = (idx < cnt);
        const int  row = slist[act ? idx : base];   // base < cnt, safe
        const float4 xv =
            *reinterpret_cast<const float4*>(hb + (size_t)row * kD + dq * 4);
        float ss = xv.x * xv.x + xv.y * xv.y + xv.z * xv.z + xv.w * xv.w;
        // reduce ||row||^2 over the 16 lanes of this row (lane bits 0..3)
        ss += __shfl_xor(ss, 1);
        ss += __shfl_xor(ss, 2);
        ss += __shfl_xor(ss, 4);
        ss += __shfl_xor(ss, 8);
        const float vf = act ? rsqrtf(fmaxf(ss, 1e-12f)) : 0.f;
        acc[0] = fmaf(xv.x, vf, acc[0]);
        acc[1] = fmaf(xv.y, vf, acc[1]);
        acc[2] = fmaf(xv.z, vf, acc[2]);
        acc[3] = fmaf(xv.w, vf, acc[3]);
    }
    // reduce across the 4 row-slots (lane bits 4,5)
#pragma unroll
    for (int j = 0; j < 4; ++j) {
        acc[j] += __shfl_xor(acc[j], 16);
        acc[j] += __shfl_xor(acc[j], 32);
    }
    if (sub == 0) {
#pragma unroll
        for (int j = 0; j < 4; ++j) sacc[wave][dq * 4 + j] = acc[j];
    }
    __syncthreads();

    if (tid < kD) {
        atomicAdd(&gacc[b * kAccStride + tid],
                  sacc[0][tid] + sacc[1][tid] + sacc[2][tid] + sacc[3][tid]);
    }
    if (tid == 0) {
        atomicAdd(&gacc[b * kAccStride + kD], (float)cnt);
    }
}

// Kernel 2: one wave per (b,r): s = <l_hat, v_b>, then fusion weight.
__global__ __launch_bounds__(256) void ssfw_out(
    const float* __restrict__ l,               // [B,R,D] f32
    const float* __restrict__ lam,             // [R,O] f32
    const int* __restrict__ center_o,          // [B] int32
    const float* __restrict__ gacc,            // [B, kAccStride]
    float* __restrict__ out)                   // [B,R] f32
{
    const int task = (blockIdx.x << 2) + (threadIdx.x >> 6); // wave id in [0,B*R)
    const int lane = threadIdx.x & 63;
    const int b = task >> 5;      // / kR
    const int r = task & 31;      // % kR

    const float x  = l[((size_t)(b * kR + r)) * kD + lane];
    const float v  = gacc[b * kAccStride + lane];
    const float nv = gacc[b * kAccStride + kD];

    float ss = x * x;
    float dt = x * v;
#pragma unroll
    for (int m = 1; m < 64; m <<= 1) {
        ss += __shfl_xor(ss, m);
        dt += __shfl_xor(dt, m);
    }

    if (lane == 0) {
        const int ctr  = center_o[b];
        const float rinv = rsqrtf(fmaxf(ss, 1e-12f));
        const float s    = dt * rinv;                 // sum of masked cos sims
        const float avg  = s / fmaxf(nv, 1e-9f);
        const float lamv = lam[r * kO + ctr];
        const float w = fmaxf(lamv / fmaxf(nv, 1.f), 0.f) * (1.f - avg);
        out[b * kR + r] = w;
    }
}

extern "C" void kernel_launch(void* const* d_in, const int* in_sizes, int n_in,
                              void* d_out, int out_size, void* d_ws, size_t ws_size,
                              hipStream_t stream) {
    const float* l_local   = (const float*)d_in[0];   // f32 [B,R,D]
    const float* h_context = (const float*)d_in[1];   // f32 [B,N,D]
    const float* lambda_so = (const float*)d_in[2];   // f32 [R,O]
    const int* center_o = (const int*)d_in[3];        // [B]
    const int* o_types  = (const int*)d_in[4];        // [B,N]
    const void* adj     = d_in[5];                    // [B,N] int32 or byte
    const void* two     = d_in[6];                    // [B,N] int32 or byte

    float* gacc = (float*)d_ws;                        // [B, kAccStride] fp32
    int*   flag = (int*)((char*)d_ws + kFlagOff);      // mask-dtype flag
    hipMemsetAsync(d_ws, 0, kFlagOff + sizeof(int), stream);

    ssfw_detect<<<256, 256, 0, stream>>>((const unsigned*)adj, (const unsigned*)two, flag);

    dim3 grid1(kChunks, kB);
    ssfw_accum<<<grid1, 256, 0, stream>>>(h_context, o_types, center_o, adj, two,
                                          flag, gacc);

    ssfw_out<<<(kB * kR) / 4, 256, 0, stream>>>(l_local, lambda_so, center_o, gacc,
                                                (float*)d_out);
}

// Round 4
// 314.987 us; speedup vs baseline: 1.0126x; 1.0126x over previous
//
#include <hip/hip_runtime.h>

// (B,R,N,D,O) = (64,32,16384,64,8)
// Dtype model (verified R3 pass): float tensors fp32, o_types/center_o int32,
// masks int32-or-byte (runtime-detected), output fp32 (compared after bf16 round).
constexpr int kB = 64;
constexpr int kR = 32;
constexpr int kN = 16384;
constexpr int kD = 64;
constexpr int kO = 8;
constexpr int kChunks = 16;                    // accum blocks per batch
constexpr int kRowsPerBlock = kN / kChunks;    // 1024
constexpr int kPartStride = kD + 1;            // 64 sums + count per (b,chunk)
constexpr int kMaskWords = kB * kN / 4;        // first B*N bytes viewed as u32
constexpr unsigned kByteMagic = 0x42424242u;
// ws layout: part[B][kChunks][kPartStride] f32, then 1 flag word.
constexpr size_t kFlagOff = (size_t)kB * kChunks * kPartStride * sizeof(float);

// Mask-dtype detect: byte-bool arrays contain u32 words >1 with ~14%/word;
// int32 0/1 arrays never do. No init needed: flag's harness 0xAA poison (or a
// stale magic from a previous byte-mode launch) is only ever equal to
// kByteMagic when byte masks were detected -> accum tests equality to magic.
__global__ __launch_bounds__(256) void ssfw_detect(
    const unsigned* __restrict__ adj, const unsigned* __restrict__ two,
    unsigned* __restrict__ flag)
{
    int any = 0;
    for (int i = blockIdx.x * blockDim.x + threadIdx.x; i < kMaskWords;
         i += gridDim.x * blockDim.x) {
        any |= (adj[i] > 1u) | (two[i] > 1u);
    }
    if (__any(any)) {
        if ((threadIdx.x & 63) == 0) atomicExch(flag, kByteMagic);
    }
}

// Accum: per (b,chunk): scan masks, list valid rows (~0.74%) in LDS, then
// sum h[row,:]/||h[row]|| over them. Plain stores to private partial slot —
// no global atomics, no zero-init required.
__global__ __launch_bounds__(256) void ssfw_accum(
    const float* __restrict__ h,               // [B,N,D] f32
    const int* __restrict__ o_types,           // [B,N] int32
    const int* __restrict__ center_o,          // [B] int32
    const void* __restrict__ adj,              // [B,N] int32 or byte bool
    const void* __restrict__ two,              // [B,N] int32 or byte bool
    const unsigned* __restrict__ flag,
    float* __restrict__ part)                  // [B][kChunks][kPartStride]
{
    const int b     = blockIdx.y;
    const int chunk = blockIdx.x;
    const int tid   = threadIdx.x;
    const int wave  = tid >> 6;
    const int lane  = tid & 63;
    const int sub   = lane >> 4;   // which of 4 rows this lane helps with
    const int dq    = lane & 15;   // which float4 of the 64-float row

    const int  ctr      = center_o[b];
    const bool bytemask = (*flag == kByteMagic);
    const int  row0     = chunk * kRowsPerBlock;
    const float* hb     = h + (size_t)b * kN * kD;

    __shared__ int   slist[kRowsPerBlock];
    __shared__ int   lcnt;
    __shared__ float sacc[4][kD];

    if (tid == 0) lcnt = 0;
    __syncthreads();

    // Phase A: mask scan — thread t checks rows r..r+3.
    {
        const int r = row0 + tid * 4;
        const size_t base = (size_t)b * kN + r;
        int a[4], t[4];
        if (bytemask) {
            const unsigned aw = reinterpret_cast<const unsigned*>(adj)[base >> 2];
            const unsigned tw = reinterpret_cast<const unsigned*>(two)[base >> 2];
            a[0] = aw & 0xff; a[1] = (aw >> 8) & 0xff;
            a[2] = (aw >> 16) & 0xff; a[3] = aw >> 24;
            t[0] = tw & 0xff; t[1] = (tw >> 8) & 0xff;
            t[2] = (tw >> 16) & 0xff; t[3] = tw >> 24;
        } else {
            const int4 a4 = reinterpret_cast<const int4*>(adj)[base >> 2];
            const int4 t4 = reinterpret_cast<const int4*>(two)[base >> 2];
            a[0] = a4.x; a[1] = a4.y; a[2] = a4.z; a[3] = a4.w;
            t[0] = t4.x; t[1] = t4.y; t[2] = t4.z; t[3] = t4.w;
        }
        const int4 o4 = reinterpret_cast<const int4*>(o_types)[base >> 2];
        const int oo[4] = {o4.x, o4.y, o4.z, o4.w};
#pragma unroll
        for (int k = 0; k < 4; ++k) {
            if (((a[k] | t[k]) != 0) && (oo[k] == ctr)) {
                const int p = atomicAdd(&lcnt, 1);
                slist[p] = r + k;
            }
        }
    }
    __syncthreads();
    const int cnt = lcnt;

    // Phase B: 4 rows per wave-iter, 16 lanes per row (float4 each).
    float acc[4] = {0.f, 0.f, 0.f, 0.f};
    for (int base = wave * 4; base < cnt; base += 16) {
        const int  idx = base + sub;
        const bool act = (idx < cnt);
        const int  row = slist[act ? idx : base];   // base < cnt, safe
        const float4 xv =
            *reinterpret_cast<const float4*>(hb + (size_t)row * kD + dq * 4);
        float ss = xv.x * xv.x + xv.y * xv.y + xv.z * xv.z + xv.w * xv.w;
        ss += __shfl_xor(ss, 1);
        ss += __shfl_xor(ss, 2);
        ss += __shfl_xor(ss, 4);
        ss += __shfl_xor(ss, 8);
        const float vf = act ? rsqrtf(fmaxf(ss, 1e-12f)) : 0.f;
        acc[0] = fmaf(xv.x, vf, acc[0]);
        acc[1] = fmaf(xv.y, vf, acc[1]);
        acc[2] = fmaf(xv.z, vf, acc[2]);
        acc[3] = fmaf(xv.w, vf, acc[3]);
    }
#pragma unroll
    for (int j = 0; j < 4; ++j) {
        acc[j] += __shfl_xor(acc[j], 16);
        acc[j] += __shfl_xor(acc[j], 32);
    }
    if (sub == 0) {
#pragma unroll
        for (int j = 0; j < 4; ++j) sacc[wave][dq * 4 + j] = acc[j];
    }
    __syncthreads();

    float* slot = part + ((size_t)b * kChunks + chunk) * kPartStride;
    if (tid < kD) {
        slot[tid] = sacc[0][tid] + sacc[1][tid] + sacc[2][tid] + sacc[3][tid];
    }
    if (tid == kD) {
        slot[kD] = (float)cnt;
    }
}

// Out: one wave per (b,r) — fold chunk partials, dot with normalized l row.
__global__ __launch_bounds__(256) void ssfw_out(
    const float* __restrict__ l,               // [B,R,D] f32
    const float* __restrict__ lam,             // [R,O] f32
    const int* __restrict__ center_o,          // [B] int32
    const float* __restrict__ part,            // [B][kChunks][kPartStride]
    float* __restrict__ out)                   // [B,R] f32
{
    const int task = (blockIdx.x << 2) + (threadIdx.x >> 6); // in [0, B*R)
    const int lane = threadIdx.x & 63;
    const int b = task >> 5;      // / kR
    const int r = task & 31;      // % kR

    const float* pb = part + (size_t)b * kChunks * kPartStride;
    float v = 0.f, nv = 0.f;
#pragma unroll
    for (int c = 0; c < kChunks; ++c) {
        v  += pb[c * kPartStride + lane];
        nv += pb[c * kPartStride + kD];
    }

    const float x = l[((size_t)(b * kR + r)) * kD + lane];
    float ss = x * x;
    float dt = x * v;
#pragma unroll
    for (int m = 1; m < 64; m <<= 1) {
        ss += __shfl_xor(ss, m);
        dt += __shfl_xor(dt, m);
    }

    if (lane == 0) {
        const int ctr  = center_o[b];
        const float rinv = rsqrtf(fmaxf(ss, 1e-12f));
        const float s    = dt * rinv;                 // sum of masked cos sims
        const float avg  = s / fmaxf(nv, 1e-9f);
        const float lamv = lam[r * kO + ctr];
        const float w = fmaxf(lamv / fmaxf(nv, 1.f), 0.f) * (1.f - avg);
        out[b * kR + r] = w;
    }
}

extern "C" void kernel_launch(void* const* d_in, const int* in_sizes, int n_in,
                              void* d_out, int out_size, void* d_ws, size_t ws_size,
                              hipStream_t stream) {
    const float* l_local   = (const float*)d_in[0];   // f32 [B,R,D]
    const float* h_context = (const float*)d_in[1];   // f32 [B,N,D]
    const float* lambda_so = (const float*)d_in[2];   // f32 [R,O]
    const int* center_o = (const int*)d_in[3];        // [B]
    const int* o_types  = (const int*)d_in[4];        // [B,N]
    const void* adj     = d_in[5];                    // [B,N] int32 or byte
    const void* two     = d_in[6];                    // [B,N] int32 or byte

    float*    part = (float*)d_ws;                       // partials
    unsigned* flag = (unsigned*)((char*)d_ws + kFlagOff);

    ssfw_detect<<<256, 256, 0, stream>>>((const unsigned*)adj,
                                         (const unsigned*)two, flag);

    dim3 grid1(kChunks, kB);
    ssfw_accum<<<grid1, 256, 0, stream>>>(h_context, o_types, center_o, adj, two,
                                          flag, part);

    ssfw_out<<<(kB * kR) / 4, 256, 0, stream>>>(l_local, lambda_so, center_o, part,
                                                (float*)d_out);
}

// Round 5
// 313.119 us; speedup vs baseline: 1.0186x; 1.0060x over previous
//
#include <hip/hip_runtime.h>

// (B,R,N,D,O) = (64,32,16384,64,8)
// Dtype model (verified R3/R4 pass): float tensors fp32, o_types/center_o int32,
// masks int32-or-byte (detected per-block below), output fp32.
constexpr int kB = 64;
constexpr int kR = 32;
constexpr int kN = 16384;
constexpr int kD = 64;
constexpr int kChunks = 16;                    // accum blocks per batch
constexpr int kRowsPerBlock = kN / kChunks;    // 1024
constexpr int kPartStride = kD + 1;            // 64 sums + count per (b,chunk)
constexpr int kO = 8;

// Accum: per (b,chunk): detect mask dtype locally, scan masks, list valid rows
// (~0.74%) in LDS, then sum h[row,:]/||h[row]|| over them. Plain stores to a
// private partial slot — no global atomics, no zero-init, no detect kernel.
//
// Local dtype detection: this block's Phase-A byte-layout word range
// [(b*N+row0)/4, +256) is in-bounds under BOTH layouts (max word index
// 262143 <= byte-buffer 262144 words, int32-buffer 1M words). Byte-bool
// arrays yield words >1 with P~17%/word (two) — P(no evidence over 512
// words | byte) ~ 4e-24 per block. If no evidence: masks are int32 0/1.
__global__ __launch_bounds__(256) void ssfw_accum(
    const float* __restrict__ h,               // [B,N,D] f32
    const int* __restrict__ o_types,           // [B,N] int32
    const int* __restrict__ center_o,          // [B] int32
    const void* __restrict__ adj,              // [B,N] int32 or byte bool
    const void* __restrict__ two,              // [B,N] int32 or byte bool
    float* __restrict__ part)                  // [B][kChunks][kPartStride]
{
    const int b     = blockIdx.y;
    const int chunk = blockIdx.x;
    const int tid   = threadIdx.x;
    const int wave  = tid >> 6;
    const int lane  = tid & 63;
    const int sub   = lane >> 4;   // which of 4 rows this lane helps with
    const int dq    = lane & 15;   // which float4 of the 64-float row

    const int  ctr  = center_o[b];
    const int  row0 = chunk * kRowsPerBlock;
    const float* hb = h + (size_t)b * kN * kD;

    __shared__ int   slist[kRowsPerBlock];
    __shared__ int   lcnt;
    __shared__ int   sev[4];
    __shared__ float sacc[4][kD];

    if (tid == 0) lcnt = 0;

    // Probe words (byte-layout addresses for this block's rows; in-bounds
    // under both layouts). One word covers this thread's 4 rows in byte mode.
    const size_t wbase = ((size_t)b * kN + row0) / 4 + tid;
    const unsigned aw = reinterpret_cast<const unsigned*>(adj)[wbase];
    const unsigned tw = reinterpret_cast<const unsigned*>(two)[wbase];
    const int ev = (aw > 1u) | (tw > 1u);
    if (lane == 0) sev[wave] = 0;
    __syncthreads();
    if (__any(ev) && lane == 0) sev[wave] = 1;
    __syncthreads();
    const bool bytemask = (sev[0] | sev[1] | sev[2] | sev[3]) != 0;

    // Phase A: mask scan — thread t checks rows r..r+3.
    {
        const int r = row0 + tid * 4;
        const size_t base = (size_t)b * kN + r;
        int a[4], t[4];
        if (bytemask) {
            a[0] = aw & 0xff; a[1] = (aw >> 8) & 0xff;
            a[2] = (aw >> 16) & 0xff; a[3] = aw >> 24;
            t[0] = tw & 0xff; t[1] = (tw >> 8) & 0xff;
            t[2] = (tw >> 16) & 0xff; t[3] = tw >> 24;
        } else {
            const int4 a4 = reinterpret_cast<const int4*>(adj)[base >> 2];
            const int4 t4 = reinterpret_cast<const int4*>(two)[base >> 2];
            a[0] = a4.x; a[1] = a4.y; a[2] = a4.z; a[3] = a4.w;
            t[0] = t4.x; t[1] = t4.y; t[2] = t4.z; t[3] = t4.w;
        }
        const int4 o4 = reinterpret_cast<const int4*>(o_types)[base >> 2];
        const int oo[4] = {o4.x, o4.y, o4.z, o4.w};
#pragma unroll
        for (int k = 0; k < 4; ++k) {
            if (((a[k] | t[k]) != 0) && (oo[k] == ctr)) {
                const int p = atomicAdd(&lcnt, 1);
                slist[p] = r + k;
            }
        }
    }
    __syncthreads();
    const int cnt = lcnt;

    // Phase B: 4 rows per wave-iter, 16 lanes per row (float4 each).
    float acc[4] = {0.f, 0.f, 0.f, 0.f};
    for (int base = wave * 4; base < cnt; base += 16) {
        const int  idx = base + sub;
        const bool act = (idx < cnt);
        const int  row = slist[act ? idx : base];   // base < cnt, safe
        const float4 xv =
            *reinterpret_cast<const float4*>(hb + (size_t)row * kD + dq * 4);
        float ss = xv.x * xv.x + xv.y * xv.y + xv.z * xv.z + xv.w * xv.w;
        ss += __shfl_xor(ss, 1);
        ss += __shfl_xor(ss, 2);
        ss += __shfl_xor(ss, 4);
        ss += __shfl_xor(ss, 8);
        const float vf = act ? rsqrtf(fmaxf(ss, 1e-12f)) : 0.f;
        acc[0] = fmaf(xv.x, vf, acc[0]);
        acc[1] = fmaf(xv.y, vf, acc[1]);
        acc[2] = fmaf(xv.z, vf, acc[2]);
        acc[3] = fmaf(xv.w, vf, acc[3]);
    }
#pragma unroll
    for (int j = 0; j < 4; ++j) {
        acc[j] += __shfl_xor(acc[j], 16);
        acc[j] += __shfl_xor(acc[j], 32);
    }
    if (sub == 0) {
#pragma unroll
        for (int j = 0; j < 4; ++j) sacc[wave][dq * 4 + j] = acc[j];
    }
    __syncthreads();

    float* slot = part + ((size_t)b * kChunks + chunk) * kPartStride;
    if (tid < kD) {
        slot[tid] = sacc[0][tid] + sacc[1][tid] + sacc[2][tid] + sacc[3][tid];
    }
    if (tid == kD) {
        slot[kD] = (float)cnt;
    }
}

// Out: one wave per (b,r) — fold chunk partials, dot with normalized l row.
__global__ __launch_bounds__(256) void ssfw_out(
    const float* __restrict__ l,               // [B,R,D] f32
    const float* __restrict__ lam,             // [R,O] f32
    const int* __restrict__ center_o,          // [B] int32
    const float* __restrict__ part,            // [B][kChunks][kPartStride]
    float* __restrict__ out)                   // [B,R] f32
{
    const int task = (blockIdx.x << 2) + (threadIdx.x >> 6); // in [0, B*R)
    const int lane = threadIdx.x & 63;
    const int b = task >> 5;      // / kR
    const int r = task & 31;      // % kR

    const float* pb = part + (size_t)b * kChunks * kPartStride;
    float v = 0.f, nv = 0.f;
#pragma unroll
    for (int c = 0; c < kChunks; ++c) {
        v  += pb[c * kPartStride + lane];
        nv += pb[c * kPartStride + kD];
    }

    const float x = l[((size_t)(b * kR + r)) * kD + lane];
    float ss = x * x;
    float dt = x * v;
#pragma unroll
    for (int m = 1; m < 64; m <<= 1) {
        ss += __shfl_xor(ss, m);
        dt += __shfl_xor(dt, m);
    }

    if (lane == 0) {
        const int ctr  = center_o[b];
        const float rinv = rsqrtf(fmaxf(ss, 1e-12f));
        const float s    = dt * rinv;                 // sum of masked cos sims
        const float avg  = s / fmaxf(nv, 1e-9f);
        const float lamv = lam[r * kO + ctr];
        const float w = fmaxf(lamv / fmaxf(nv, 1.f), 0.f) * (1.f - avg);
        out[b * kR + r] = w;
    }
}

extern "C" void kernel_launch(void* const* d_in, const int* in_sizes, int n_in,
                              void* d_out, int out_size, void* d_ws, size_t ws_size,
                              hipStream_t stream) {
    const float* l_local   = (const float*)d_in[0];   // f32 [B,R,D]
    const float* h_context = (const float*)d_in[1];   // f32 [B,N,D]
    const float* lambda_so = (const float*)d_in[2];   // f32 [R,O]
    const int* center_o = (const int*)d_in[3];        // [B]
    const int* o_types  = (const int*)d_in[4];        // [B,N]
    const void* adj     = d_in[5];                    // [B,N] int32 or byte
    const void* two     = d_in[6];                    // [B,N] int32 or byte

    float* part = (float*)d_ws;                       // partials

    dim3 grid1(kChunks, kB);
    ssfw_accum<<<grid1, 256, 0, stream>>>(h_context, o_types, center_o, adj, two,
                                          part);

    ssfw_out<<<(kB * kR) / 4, 256, 0, stream>>>(l_local, lambda_so, center_o, part,
                                                (float*)d_out);
}